// Round 7
// baseline (338.701 us; speedup 1.0000x reference)
//
#include <hip/hip_runtime.h>
#include <hip/hip_bf16.h>

// Shapes (fixed for this problem)
#define S_LEN 2048
#define HIDDIM 2048
#define NH 16
#define NKV 4
#define HD 128
#define KVROW 1024   // KVb row = [K(512) | V(512)]
#define QKVN 3072    // fused projection width

typedef __attribute__((ext_vector_type(8))) short short8;
typedef __attribute__((ext_vector_type(8))) unsigned short ushort8;
typedef __attribute__((ext_vector_type(4))) float f32x4;

__device__ __forceinline__ unsigned short f2bf(float f) {
  union { float f; unsigned int u; } v; v.f = f;
  unsigned int r = (v.u + 0x7FFFu + ((v.u >> 16) & 1u)) >> 16;
  return (unsigned short)r;
}
__device__ __forceinline__ float bf2f(unsigned short h) {
  union { unsigned int u; float f; } v; v.u = ((unsigned int)h) << 16;
  return v.f;
}

// ---------------------------------------------------------------------------
// hidden fp32 -> bf16 (vectorized 8/thread)
// ---------------------------------------------------------------------------
__global__ __launch_bounds__(256) void h2b_kernel(const float* __restrict__ H,
                                                  unsigned short* __restrict__ Hb) {
  int i = (blockIdx.x * 256 + threadIdx.x) * 8;
  float4 a = *(const float4*)(H + i), b = *(const float4*)(H + i + 4);
  ushort8 r;
  r[0] = f2bf(a.x); r[1] = f2bf(a.y); r[2] = f2bf(a.z); r[3] = f2bf(a.w);
  r[4] = f2bf(b.x); r[5] = f2bf(b.y); r[6] = f2bf(b.z); r[7] = f2bf(b.w);
  *(ushort8*)(Hb + i) = r;
}

// ---------------------------------------------------------------------------
// Weight transpose: W[k][n] fp32 (row stride Nsrc) -> Wt[n_off+n][k] bf16
// (row stride Kdst). 64x64 tiles via LDS.
// ---------------------------------------------------------------------------
__global__ __launch_bounds__(256) void transpose_w(
    const float* __restrict__ W, unsigned short* __restrict__ Wt,
    int Nsrc, int Kdst, int n_off) {
  __shared__ unsigned short Ts[64][72];
  const int n0 = blockIdx.x * 64, k0 = blockIdx.y * 64;
  const int tid = threadIdx.x;
  const int c2 = (tid & 31) * 2, rb = tid >> 5;
#pragma unroll
  for (int p = 0; p < 8; ++p) {
    int r = rb + p * 8;
    float2 v = *(const float2*)&W[(size_t)(k0 + r) * Nsrc + n0 + c2];
    Ts[c2][r] = f2bf(v.x);
    Ts[c2 + 1][r] = f2bf(v.y);
  }
  __syncthreads();
  const int n = tid >> 2, kq = (tid & 3) * 16;
  ushort8 w0 = *(const ushort8*)&Ts[n][kq];
  ushort8 w1 = *(const ushort8*)&Ts[n][kq + 8];
  size_t base = (size_t)(n_off + n0 + n) * Kdst + k0 + kq;
  *(ushort8*)&Wt[base] = w0;
  *(ushort8*)&Wt[base + 8] = w1;
}

// ---------------------------------------------------------------------------
// V transpose: KVb[s][512+c] (bf16) -> Vt[c][s] (bf16), c<512, s<2048.
// ---------------------------------------------------------------------------
__global__ __launch_bounds__(256) void transpose_v(
    const unsigned short* __restrict__ KVb, unsigned short* __restrict__ Vt) {
  __shared__ unsigned short Ts[64][72];
  const int c0 = blockIdx.x * 64, s0 = blockIdx.y * 64;
  const int tid = threadIdx.x;
  const int sr = tid >> 2, cq = (tid & 3) * 16;
  ushort8 a = *(const ushort8*)&KVb[(size_t)(s0 + sr) * KVROW + 512 + c0 + cq];
  ushort8 b = *(const ushort8*)&KVb[(size_t)(s0 + sr) * KVROW + 512 + c0 + cq + 8];
#pragma unroll
  for (int j = 0; j < 8; ++j) { Ts[cq + j][sr] = a[j]; Ts[cq + 8 + j][sr] = b[j]; }
  __syncthreads();
  const int c = tid >> 2, sq = (tid & 3) * 16;
  ushort8 w0 = *(const ushort8*)&Ts[c][sq];
  ushort8 w1 = *(const ushort8*)&Ts[c][sq + 8];
  *(ushort8*)&Vt[(size_t)(c0 + c) * S_LEN + s0 + sq] = w0;
  *(ushort8*)&Vt[(size_t)(c0 + c) * S_LEN + s0 + sq + 8] = w1;
}

// ---------------------------------------------------------------------------
// MFMA GEMM (TN): C = A[M,K] @ Bt[N,K]^T, bf16 A. BM=128, BN=64, BK=64.
// ---------------------------------------------------------------------------
template <bool CF>
__global__ __launch_bounds__(256) void gemm_tn(
    const unsigned short* __restrict__ A, const unsigned short* __restrict__ Bt,
    void* __restrict__ C1, void* __restrict__ C2,
    int M, int N, int K, int splitcol, int ld1, int ld2) {
  __shared__ unsigned short As[128][72];
  __shared__ unsigned short Bs[64][72];
  const int m0 = blockIdx.y * 128, n0 = blockIdx.x * 64;
  const int tid = threadIdx.x, wid = tid >> 6, lane = tid & 63;
  const int wr = wid >> 1, wc = wid & 1;
  const int lr = lane & 15, lg = lane >> 4;

  f32x4 acc[4][2];
#pragma unroll
  for (int m = 0; m < 4; ++m)
#pragma unroll
    for (int n = 0; n < 2; ++n) acc[m][n] = (f32x4){0.f, 0.f, 0.f, 0.f};

  const int ar = tid >> 1, ac = (tid & 1) * 32;  // A: 128 rows x 2 half-rows
  const int br = tid >> 2, bc = (tid & 3) * 16;  // B: 64 rows x 4 chunks

  ushort8 areg[4], breg[2];
  auto loadA = [&](int k0) {
#pragma unroll
    for (int i = 0; i < 4; ++i)
      areg[i] = *(const ushort8*)(A + (size_t)(m0 + ar) * K + k0 + ac + i * 8);
  };
  auto loadB = [&](int k0) {
    breg[0] = *(const ushort8*)(Bt + (size_t)(n0 + br) * K + k0 + bc);
    breg[1] = *(const ushort8*)(Bt + (size_t)(n0 + br) * K + k0 + bc + 8);
  };
  auto writeS = [&]() {
#pragma unroll
    for (int i = 0; i < 4; ++i) *(ushort8*)&As[ar][ac + i * 8] = areg[i];
    *(ushort8*)&Bs[br][bc] = breg[0];
    *(ushort8*)&Bs[br][bc + 8] = breg[1];
  };

  loadA(0); loadB(0);
  writeS();

  for (int k0 = 0; k0 < K; k0 += 64) {
    __syncthreads();
    if (k0 + 64 < K) { loadA(k0 + 64); loadB(k0 + 64); }
#pragma unroll
    for (int s = 0; s < 2; ++s) {
      short8 af[4], bfv[2];
#pragma unroll
      for (int m = 0; m < 4; ++m)
        af[m] = *(const short8*)&As[wr * 64 + m * 16 + lr][s * 32 + lg * 8];
#pragma unroll
      for (int n = 0; n < 2; ++n)
        bfv[n] = *(const short8*)&Bs[wc * 32 + n * 16 + lr][s * 32 + lg * 8];
#pragma unroll
      for (int m = 0; m < 4; ++m)
#pragma unroll
        for (int n = 0; n < 2; ++n)
          acc[m][n] = __builtin_amdgcn_mfma_f32_16x16x32_bf16(af[m], bfv[n], acc[m][n], 0, 0, 0);
    }
    __syncthreads();
    if (k0 + 64 < K) writeS();
  }

#pragma unroll
  for (int m = 0; m < 4; ++m)
#pragma unroll
    for (int n = 0; n < 2; ++n)
#pragma unroll
      for (int r = 0; r < 4; ++r) {
        int row = m0 + wr * 64 + m * 16 + lg * 4 + r;
        int col = n0 + wc * 32 + n * 16 + lr;
        float v = acc[m][n][r];
        if (CF) ((float*)C1)[(size_t)row * ld1 + col] = v;
        else if (col < splitcol) ((unsigned short*)C1)[(size_t)row * ld1 + col] = f2bf(v);
        else ((unsigned short*)C2)[(size_t)row * ld2 + (col - splitcol)] = f2bf(v);
      }
}

// ---------------------------------------------------------------------------
// RoPE: one thread per (s, j), trig once, applied to 16 Q + 4 K heads.
// ---------------------------------------------------------------------------
__global__ void rope2(unsigned short* __restrict__ Q,
                      unsigned short* __restrict__ KV,
                      const int* __restrict__ pos) {
  int idx = blockIdx.x * blockDim.x + threadIdx.x;
  if (idx >= S_LEN * 64) return;
  int s = idx >> 6, j = idx & 63;
  float inv = exp2f(-0.2076205059304703f * (float)j);  // 10000^(-j/64)
  float ang = (float)pos[s] * inv;
  float sn, cs;
  __sincosf(ang, &sn, &cs);
  auto rot = [&](unsigned short* base) {
    unsigned* p = (unsigned*)base;
    unsigned v = *p;
    float x0 = bf2f((unsigned short)(v & 0xffff));
    float x1 = bf2f((unsigned short)(v >> 16));
    unsigned r = (unsigned)f2bf(x0 * cs - x1 * sn) |
                 ((unsigned)f2bf(x0 * sn + x1 * cs) << 16);
    *p = r;
  };
#pragma unroll
  for (int hh = 0; hh < NH; ++hh) rot(Q + (size_t)s * HIDDIM + hh * HD + 2 * j);
#pragma unroll
  for (int hh = 0; hh < NKV; ++hh) rot(KV + (size_t)s * KVROW + hh * HD + 2 * j);
}

// ---------------------------------------------------------------------------
// Compact attention_mask [S] int32 -> bitmask words (1 bit per key).
// ---------------------------------------------------------------------------
__global__ void maskbits_kernel(const int* __restrict__ amask,
                                unsigned* __restrict__ mb) {
  int w = threadIdx.x;  // 64 words
  unsigned m = 0;
#pragma unroll
  for (int b = 0; b < 32; ++b) m |= (amask[w * 32 + b] != 0 ? 1u : 0u) << b;
  mb[w] = m;
}

// ---------------------------------------------------------------------------
// Flash attention v6: no LDS / no barriers, but EXPLICIT register pipelining:
// K double-buffered in regs (prefetch issued between QK and softmax); V
// single-buffered, issued at tile top (consumed after QK+softmax). Manual
// 2x unroll with statically named buffers (no runtime-indexed reg arrays).
// Swapped QK^T, static-max softmax, shfl P-exchange, 2-way k-split.
// ---------------------------------------------------------------------------
__global__ __launch_bounds__(256) void attn_kernel(
    const unsigned short* __restrict__ Qb, const unsigned short* __restrict__ KVb,
    const unsigned short* __restrict__ Vt, const unsigned* __restrict__ mbits,
    unsigned short* __restrict__ Ob,
    unsigned short* __restrict__ Opart, float* __restrict__ Lpart, int nsplit) {
  const int h = blockIdx.y;
  const int qt = (int)(gridDim.x - 1 - blockIdx.x);  // LPT: longest first
  const int qb = qt * 64;
  const int z = (int)blockIdx.z;
  const int nk = qb + 64;
  int kbeg = 0, kend = nk;
  bool partial = false;
  if (nsplit == 2 && nk > 1024) {
    kbeg = z * 1024;
    kend = min(nk, kbeg + 1024);
    partial = true;
  } else if (z != 0) {
    return;
  }

  const int kvh = h >> 2;
  const int tid = threadIdx.x, wid = tid >> 6, lane = tid & 63;
  const int lr = lane & 15, lg = lane >> 4;

  const unsigned short* Kp = KVb + kvh * HD;                  // K[s][d]
  const unsigned short* Vp = Vt + (size_t)(kvh * HD) * S_LEN; // Vt[d][s]

  short8 qf[4];
  {
    const unsigned short* qp = Qb + (size_t)(qb + wid * 16 + lr) * HIDDIM + h * HD;
#pragma unroll
    for (int c = 0; c < 4; ++c) qf[c] = *(const short8*)(qp + c * 32 + lg * 8);
  }
  f32x4 o[8];
#pragma unroll
  for (int c = 0; c < 8; ++c) o[c] = (f32x4){0.f, 0.f, 0.f, 0.f};
  float lsum = 0.f;

  const int qr = qb + wid * 16 + lr;                 // this lane's q-row
  const int kend_w = min(kend, qb + wid * 16 + 16);  // wave's causal end
  const float SCALE = 0.08838834764831845f;

  short8 ka[8], kb[8], vv[8];  // K dbuf (t*4+c), V single buffer

  auto loadK = [&](int kt, short8 (&kf)[8]) {
#pragma unroll
    for (int t = 0; t < 2; ++t)
#pragma unroll
      for (int c = 0; c < 4; ++c)
        kf[t * 4 + c] = *(const short8*)(Kp + (size_t)(kt + t * 16 + lr) * KVROW +
                                         c * 32 + lg * 8);
  };
  auto loadV = [&](int kt) {
#pragma unroll
    for (int c = 0; c < 8; ++c)
      vv[c] = *(const short8*)(Vp + (size_t)(c * 16 + lr) * S_LEN + kt + lg * 8);
  };

  // One tile: issue V(kt) first, QK with kc, prefetch K(kt+32)->kn under
  // softmax, exchange, PV with vv.
  auto tile = [&](int kt, const short8 (&kc)[8], short8 (&kn)[8], bool pref) {
    loadV(kt);
    f32x4 sc0 = (f32x4){0.f, 0.f, 0.f, 0.f};
    f32x4 sc1 = (f32x4){0.f, 0.f, 0.f, 0.f};
#pragma unroll
    for (int c = 0; c < 4; ++c)
      sc0 = __builtin_amdgcn_mfma_f32_16x16x32_bf16(kc[c], qf[c], sc0, 0, 0, 0);
#pragma unroll
    for (int c = 0; c < 4; ++c)
      sc1 = __builtin_amdgcn_mfma_f32_16x16x32_bf16(kc[4 + c], qf[c], sc1, 0, 0, 0);
    if (pref) loadK(kt + 32, kn);
    const unsigned mw = mbits[kt >> 5];
    float p[2][4];
#pragma unroll
    for (int r = 0; r < 4; ++r) {
      int kk = lg * 4 + r;
      bool ok = (kt + kk <= qr) && ((mw >> kk) & 1u);
      float s = ok ? sc0[r] * SCALE - 3.0f : -1e30f;
      float pv = __expf(s);
      p[0][r] = pv; lsum += pv;
    }
#pragma unroll
    for (int r = 0; r < 4; ++r) {
      int kk = 16 + lg * 4 + r;
      bool ok = (kt + kk <= qr) && ((mw >> kk) & 1u);
      float s = ok ? sc1[r] * SCALE - 3.0f : -1e30f;
      float pv = __expf(s);
      p[1][r] = pv; lsum += pv;
    }
    unsigned W0 = (unsigned)f2bf(p[0][0]) | ((unsigned)f2bf(p[0][1]) << 16);
    unsigned W1 = (unsigned)f2bf(p[0][2]) | ((unsigned)f2bf(p[0][3]) << 16);
    unsigned W2 = (unsigned)f2bf(p[1][0]) | ((unsigned)f2bf(p[1][1]) << 16);
    unsigned W3 = (unsigned)f2bf(p[1][2]) | ((unsigned)f2bf(p[1][3]) << 16);
    const int s0 = lr + ((lg & 1) << 5);
    const int s1 = s0 + 16;
    unsigned x0 = __shfl(W0, s0, 64), y0 = __shfl(W2, s0, 64);
    unsigned x1 = __shfl(W1, s0, 64), y1 = __shfl(W3, s0, 64);
    unsigned x2 = __shfl(W0, s1, 64), y2 = __shfl(W2, s1, 64);
    unsigned x3 = __shfl(W1, s1, 64), y3 = __shfl(W3, s1, 64);
    union { unsigned u[4]; short8 s8; } pu;
    const bool lo = (lg < 2);
    pu.u[0] = lo ? x0 : y0;
    pu.u[1] = lo ? x1 : y1;
    pu.u[2] = lo ? x2 : y2;
    pu.u[3] = lo ? x3 : y3;
    short8 pf = pu.s8;
#pragma unroll
    for (int c = 0; c < 8; ++c)
      o[c] = __builtin_amdgcn_mfma_f32_16x16x32_bf16(pf, vv[c], o[c], 0, 0, 0);
  };

  const int nt = (kend_w - kbeg + 31) >> 5;
  int kt = kbeg, i = 0;
  loadK(kbeg, ka);
  while (true) {
    tile(kt, ka, kb, i + 1 < nt);
    ++i; kt += 32;
    if (i >= nt) break;
    tile(kt, kb, ka, i + 1 < nt);
    ++i; kt += 32;
    if (i >= nt) break;
  }

  // Row-sum totals: lanes {lr, lr+16, lr+32, lr+48} hold key-disjoint partials.
  float ls = lsum;
  ls += __shfl_xor(ls, 16, 64);
  ls += __shfl_xor(ls, 32, 64);

  if (!partial) {
    float lrec[4];
#pragma unroll
    for (int r = 0; r < 4; ++r) lrec[r] = 1.0f / __shfl(ls, lg * 4 + r, 16);
#pragma unroll
    for (int c = 0; c < 8; ++c)
#pragma unroll
      for (int r = 0; r < 4; ++r) {
        const int row = qb + wid * 16 + lg * 4 + r;
        Ob[(size_t)row * HIDDIM + h * HD + c * 16 + lr] = f2bf(o[c][r] * lrec[r]);
      }
  } else {
    const int slot = (((qt - 16) << 4) + h) * 2 + z;
    if (lg == 0) Lpart[slot * 64 + wid * 16 + lr] = ls;
#pragma unroll
    for (int c = 0; c < 8; ++c)
#pragma unroll
      for (int r = 0; r < 4; ++r)
        Opart[(size_t)slot * 8192 + (wid * 16 + lg * 4 + r) * 128 + c * 16 + lr] =
            f2bf(o[c][r]);
  }
}

// ---------------------------------------------------------------------------
// Combine 2 k-split partials (additive, static-max): o = (o0+o1)/(l0+l1).
// ---------------------------------------------------------------------------
__global__ __launch_bounds__(256) void combine_kernel(
    const unsigned short* __restrict__ Opart, const float* __restrict__ Lpart,
    unsigned short* __restrict__ Ob) {
  const int qt = 16 + blockIdx.x, h = blockIdx.y;
  const int slot0 = (((qt - 16) << 4) + h) * 2;
  const int tid = threadIdx.x;
  const int row = tid >> 2, d0 = (tid & 3) * 32;
  const float linv = 1.0f / (Lpart[slot0 * 64 + row] + Lpart[(slot0 + 1) * 64 + row]);
  const unsigned short* p0 = Opart + (size_t)slot0 * 8192 + row * 128 + d0;
  const unsigned short* p1 = Opart + (size_t)(slot0 + 1) * 8192 + row * 128 + d0;
  unsigned short* dst = Ob + (size_t)(qt * 64 + row) * HIDDIM + h * HD + d0;
#pragma unroll
  for (int i = 0; i < 32; i += 8) {
    ushort8 a = *(const ushort8*)(p0 + i);
    ushort8 b = *(const ushort8*)(p1 + i);
    ushort8 r;
#pragma unroll
    for (int j = 0; j < 8; ++j) r[j] = f2bf((bf2f(a[j]) + bf2f(b[j])) * linv);
    *(ushort8*)(dst + i) = r;
  }
}

// ---------------------------------------------------------------------------
extern "C" void kernel_launch(void* const* d_in, const int* in_sizes, int n_in,
                              void* d_out, int out_size, void* d_ws, size_t ws_size,
                              hipStream_t stream) {
  const float* hidden = (const float*)d_in[0];
  const float* wq = (const float*)d_in[1];
  const float* wk = (const float*)d_in[2];
  const float* wv = (const float*)d_in[3];
  const float* wo = (const float*)d_in[4];
  const int* amask = (const int*)d_in[5];
  const int* pos = (const int*)d_in[6];

  unsigned short* Qb = (unsigned short*)d_ws;              // [2048][2048] bf16
  unsigned short* KVb = Qb + (size_t)S_LEN * HIDDIM;       // [2048][1024] K|V
  unsigned short* Ab = KVb + (size_t)S_LEN * KVROW;        // [2048][2048]
  unsigned short* WT1 = Ab + (size_t)S_LEN * HIDDIM;       // [3072][2048] Wqkv^T / Wo^T
  unsigned short* Hb = WT1 + (size_t)QKVN * HIDDIM;        // [2048][2048] bf16 hidden
  unsigned* mbits = (unsigned*)(Hb + (size_t)S_LEN * HIDDIM);
  float* Lpart = (float*)(mbits + 64);                     // 512*64 f32
  unsigned short* Opart = Hb;   // alias: Hb dead after QKV gemm (8 MB = 512*16KB)
  unsigned short* Vt = WT1 + (size_t)HIDDIM * HIDDIM;      // alias WkT/WvT region,
                                                           // dead after QKV gemm
  float* out = (float*)d_out;

  size_t need = (size_t)((char*)(Lpart + 512 * 64) - (char*)d_ws);
  int nsplit = (ws_size >= need) ? 2 : 1;

  dim3 blk(256);
  h2b_kernel<<<2048, blk, 0, stream>>>(hidden, Hb);
  transpose_w<<<dim3(32, 32), blk, 0, stream>>>(wq, WT1, HIDDIM, HIDDIM, 0);
  transpose_w<<<dim3(8, 32), blk, 0, stream>>>(wk, WT1, 512, HIDDIM, 2048);
  transpose_w<<<dim3(8, 32), blk, 0, stream>>>(wv, WT1, 512, HIDDIM, 2560);
  // Fused QKV projection: cols<2048 -> Qb, else -> KVb
  gemm_tn<false><<<dim3(QKVN / 64, S_LEN / 128), blk, 0, stream>>>(
      Hb, WT1, Qb, KVb, S_LEN, QKVN, HIDDIM, 2048, HIDDIM, KVROW);
  // V transpose into dead WkT/WvT region (V is not rope'd)
  transpose_v<<<dim3(8, 32), blk, 0, stream>>>(KVb, Vt);
  // Wo^T into WT1[0..2048) (Wq^T dead after QKV gemm)
  transpose_w<<<dim3(32, 32), blk, 0, stream>>>(wo, WT1, HIDDIM, HIDDIM, 0);
  rope2<<<(S_LEN * 64 + 255) / 256, blk, 0, stream>>>(Qb, KVb, pos);
  maskbits_kernel<<<1, 64, 0, stream>>>(amask, mbits);
  // Attention (k-split when ws allows)
  attn_kernel<<<dim3(S_LEN / 64, NH, nsplit), blk, 0, stream>>>(
      Qb, KVb, Vt, mbits, Ab, Opart, Lpart, nsplit);
  if (nsplit == 2)
    combine_kernel<<<dim3(16, 16), blk, 0, stream>>>(Opart, Lpart, Ab);
  // Output projection (fp32 out)
  gemm_tn<true><<<dim3(HIDDIM / 64, S_LEN / 128), blk, 0, stream>>>(
      Ab, WT1, out, nullptr, S_LEN, HIDDIM, HIDDIM, HIDDIM, HIDDIM, 0);
}

// Round 8
// 204.924 us; speedup vs baseline: 1.6528x; 1.6528x over previous
//
#include <hip/hip_runtime.h>
#include <hip/hip_bf16.h>

// Shapes (fixed for this problem)
#define S_LEN 2048
#define HIDDIM 2048
#define NH 16
#define NKV 4
#define HD 128
#define KVROW 1024   // KVb row = [K(512) | V(512)]
#define QKVN 3072    // fused projection width

typedef __attribute__((ext_vector_type(8))) short short8;
typedef __attribute__((ext_vector_type(8))) unsigned short ushort8;
typedef __attribute__((ext_vector_type(4))) float f32x4;

__device__ __forceinline__ unsigned short f2bf(float f) {
  union { float f; unsigned int u; } v; v.f = f;
  unsigned int r = (v.u + 0x7FFFu + ((v.u >> 16) & 1u)) >> 16;
  return (unsigned short)r;
}
__device__ __forceinline__ float bf2f(unsigned short h) {
  union { unsigned int u; float f; } v; v.u = ((unsigned int)h) << 16;
  return v.f;
}

// ---------------------------------------------------------------------------
// hidden fp32 -> bf16 (vectorized 8/thread)
// ---------------------------------------------------------------------------
__global__ __launch_bounds__(256) void h2b_kernel(const float* __restrict__ H,
                                                  unsigned short* __restrict__ Hb) {
  int i = (blockIdx.x * 256 + threadIdx.x) * 8;
  float4 a = *(const float4*)(H + i), b = *(const float4*)(H + i + 4);
  ushort8 r;
  r[0] = f2bf(a.x); r[1] = f2bf(a.y); r[2] = f2bf(a.z); r[3] = f2bf(a.w);
  r[4] = f2bf(b.x); r[5] = f2bf(b.y); r[6] = f2bf(b.z); r[7] = f2bf(b.w);
  *(ushort8*)(Hb + i) = r;
}

// ---------------------------------------------------------------------------
// Weight transpose: W[k][n] fp32 (row stride Nsrc) -> Wt[n_off+n][k] bf16
// (row stride Kdst). 64x64 tiles via LDS.
// ---------------------------------------------------------------------------
__global__ __launch_bounds__(256) void transpose_w(
    const float* __restrict__ W, unsigned short* __restrict__ Wt,
    int Nsrc, int Kdst, int n_off) {
  __shared__ unsigned short Ts[64][72];
  const int n0 = blockIdx.x * 64, k0 = blockIdx.y * 64;
  const int tid = threadIdx.x;
  const int c2 = (tid & 31) * 2, rb = tid >> 5;
#pragma unroll
  for (int p = 0; p < 8; ++p) {
    int r = rb + p * 8;
    float2 v = *(const float2*)&W[(size_t)(k0 + r) * Nsrc + n0 + c2];
    Ts[c2][r] = f2bf(v.x);
    Ts[c2 + 1][r] = f2bf(v.y);
  }
  __syncthreads();
  const int n = tid >> 2, kq = (tid & 3) * 16;
  ushort8 w0 = *(const ushort8*)&Ts[n][kq];
  ushort8 w1 = *(const ushort8*)&Ts[n][kq + 8];
  size_t base = (size_t)(n_off + n0 + n) * Kdst + k0 + kq;
  *(ushort8*)&Wt[base] = w0;
  *(ushort8*)&Wt[base + 8] = w1;
}

// ---------------------------------------------------------------------------
// V transpose: KVb[s][512+c] (bf16) -> Vt[c][s] (bf16), c<512, s<2048.
// ---------------------------------------------------------------------------
__global__ __launch_bounds__(256) void transpose_v(
    const unsigned short* __restrict__ KVb, unsigned short* __restrict__ Vt) {
  __shared__ unsigned short Ts[64][72];
  const int c0 = blockIdx.x * 64, s0 = blockIdx.y * 64;
  const int tid = threadIdx.x;
  const int sr = tid >> 2, cq = (tid & 3) * 16;
  ushort8 a = *(const ushort8*)&KVb[(size_t)(s0 + sr) * KVROW + 512 + c0 + cq];
  ushort8 b = *(const ushort8*)&KVb[(size_t)(s0 + sr) * KVROW + 512 + c0 + cq + 8];
#pragma unroll
  for (int j = 0; j < 8; ++j) { Ts[cq + j][sr] = a[j]; Ts[cq + 8 + j][sr] = b[j]; }
  __syncthreads();
  const int c = tid >> 2, sq = (tid & 3) * 16;
  ushort8 w0 = *(const ushort8*)&Ts[c][sq];
  ushort8 w1 = *(const ushort8*)&Ts[c][sq + 8];
  *(ushort8*)&Vt[(size_t)(c0 + c) * S_LEN + s0 + sq] = w0;
  *(ushort8*)&Vt[(size_t)(c0 + c) * S_LEN + s0 + sq + 8] = w1;
}

// ---------------------------------------------------------------------------
// MFMA GEMM (TN): C = A[M,K] @ Bt[N,K]^T, bf16 A. BM=128, BN=64, BK=64.
// ---------------------------------------------------------------------------
template <bool CF>
__global__ __launch_bounds__(256) void gemm_tn(
    const unsigned short* __restrict__ A, const unsigned short* __restrict__ Bt,
    void* __restrict__ C1, void* __restrict__ C2,
    int M, int N, int K, int splitcol, int ld1, int ld2) {
  __shared__ unsigned short As[128][72];
  __shared__ unsigned short Bs[64][72];
  const int m0 = blockIdx.y * 128, n0 = blockIdx.x * 64;
  const int tid = threadIdx.x, wid = tid >> 6, lane = tid & 63;
  const int wr = wid >> 1, wc = wid & 1;
  const int lr = lane & 15, lg = lane >> 4;

  f32x4 acc[4][2];
#pragma unroll
  for (int m = 0; m < 4; ++m)
#pragma unroll
    for (int n = 0; n < 2; ++n) acc[m][n] = (f32x4){0.f, 0.f, 0.f, 0.f};

  const int ar = tid >> 1, ac = (tid & 1) * 32;  // A: 128 rows x 2 half-rows
  const int br = tid >> 2, bc = (tid & 3) * 16;  // B: 64 rows x 4 chunks

  ushort8 areg[4], breg[2];
  auto loadA = [&](int k0) {
#pragma unroll
    for (int i = 0; i < 4; ++i)
      areg[i] = *(const ushort8*)(A + (size_t)(m0 + ar) * K + k0 + ac + i * 8);
  };
  auto loadB = [&](int k0) {
    breg[0] = *(const ushort8*)(Bt + (size_t)(n0 + br) * K + k0 + bc);
    breg[1] = *(const ushort8*)(Bt + (size_t)(n0 + br) * K + k0 + bc + 8);
  };
  auto writeS = [&]() {
#pragma unroll
    for (int i = 0; i < 4; ++i) *(ushort8*)&As[ar][ac + i * 8] = areg[i];
    *(ushort8*)&Bs[br][bc] = breg[0];
    *(ushort8*)&Bs[br][bc + 8] = breg[1];
  };

  loadA(0); loadB(0);
  writeS();

  for (int k0 = 0; k0 < K; k0 += 64) {
    __syncthreads();
    if (k0 + 64 < K) { loadA(k0 + 64); loadB(k0 + 64); }
#pragma unroll
    for (int s = 0; s < 2; ++s) {
      short8 af[4], bfv[2];
#pragma unroll
      for (int m = 0; m < 4; ++m)
        af[m] = *(const short8*)&As[wr * 64 + m * 16 + lr][s * 32 + lg * 8];
#pragma unroll
      for (int n = 0; n < 2; ++n)
        bfv[n] = *(const short8*)&Bs[wc * 32 + n * 16 + lr][s * 32 + lg * 8];
#pragma unroll
      for (int m = 0; m < 4; ++m)
#pragma unroll
        for (int n = 0; n < 2; ++n)
          acc[m][n] = __builtin_amdgcn_mfma_f32_16x16x32_bf16(af[m], bfv[n], acc[m][n], 0, 0, 0);
    }
    __syncthreads();
    if (k0 + 64 < K) writeS();
  }

#pragma unroll
  for (int m = 0; m < 4; ++m)
#pragma unroll
    for (int n = 0; n < 2; ++n)
#pragma unroll
      for (int r = 0; r < 4; ++r) {
        int row = m0 + wr * 64 + m * 16 + lg * 4 + r;
        int col = n0 + wc * 32 + n * 16 + lr;
        float v = acc[m][n][r];
        if (CF) ((float*)C1)[(size_t)row * ld1 + col] = v;
        else if (col < splitcol) ((unsigned short*)C1)[(size_t)row * ld1 + col] = f2bf(v);
        else ((unsigned short*)C2)[(size_t)row * ld2 + (col - splitcol)] = f2bf(v);
      }
}

// ---------------------------------------------------------------------------
// RoPE: one thread per (s, j), trig once, applied to 16 Q + 4 K heads.
// ---------------------------------------------------------------------------
__global__ void rope2(unsigned short* __restrict__ Q,
                      unsigned short* __restrict__ KV,
                      const int* __restrict__ pos) {
  int idx = blockIdx.x * blockDim.x + threadIdx.x;
  if (idx >= S_LEN * 64) return;
  int s = idx >> 6, j = idx & 63;
  float inv = exp2f(-0.2076205059304703f * (float)j);  // 10000^(-j/64)
  float ang = (float)pos[s] * inv;
  float sn, cs;
  __sincosf(ang, &sn, &cs);
  auto rot = [&](unsigned short* base) {
    unsigned* p = (unsigned*)base;
    unsigned v = *p;
    float x0 = bf2f((unsigned short)(v & 0xffff));
    float x1 = bf2f((unsigned short)(v >> 16));
    unsigned r = (unsigned)f2bf(x0 * cs - x1 * sn) |
                 ((unsigned)f2bf(x0 * sn + x1 * cs) << 16);
    *p = r;
  };
#pragma unroll
  for (int hh = 0; hh < NH; ++hh) rot(Q + (size_t)s * HIDDIM + hh * HD + 2 * j);
#pragma unroll
  for (int hh = 0; hh < NKV; ++hh) rot(KV + (size_t)s * KVROW + hh * HD + 2 * j);
}

// ---------------------------------------------------------------------------
// Compact attention_mask [S] int32 -> bitmask words (1 bit per key).
// ---------------------------------------------------------------------------
__global__ void maskbits_kernel(const int* __restrict__ amask,
                                unsigned* __restrict__ mb) {
  int w = threadIdx.x;  // 64 words
  unsigned m = 0;
#pragma unroll
  for (int b = 0; b < 32; ++b) m |= (amask[w * 32 + b] != 0 ? 1u : 0u) << b;
  mb[w] = m;
}

// ---------------------------------------------------------------------------
// Flash attention v7 (= proven R5 LDS-dbuf skeleton, leaner staging):
// K tile [32][128] staged coalesced from KVb; V tile [128][32] staged
// COALESCED from the global V^T (2 ushort8 loads + 2 ds_write_b128 per
// thread — replaces 16 scalar 2B gathers). LDS double-buffered, one
// barrier/tile. Swapped QK^T, static-max softmax, shfl P-exchange,
// setprio around MFMA clusters. LPT block order, no k-split.
// ---------------------------------------------------------------------------
__global__ __launch_bounds__(256) void attn_kernel(
    const unsigned short* __restrict__ Qb, const unsigned short* __restrict__ KVb,
    const unsigned short* __restrict__ VtG, const unsigned* __restrict__ mbits,
    unsigned short* __restrict__ Ob) {
  __shared__ unsigned short Klds[2][32][136];
  __shared__ unsigned short Vlds[2][128][40];   // Vlds[d][key]
  const int h = blockIdx.y;
  const int qt = (int)(gridDim.x - 1 - blockIdx.x);  // LPT: longest first
  const int qb = qt * 64;
  const int kvh = h >> 2;
  const int tid = threadIdx.x, wid = tid >> 6, lane = tid & 63;
  const int lr = lane & 15, lg = lane >> 4;

  short8 qf[4];
  {
    const unsigned short* qp = Qb + (size_t)(qb + wid * 16 + lr) * HIDDIM + h * HD;
#pragma unroll
    for (int c = 0; c < 4; ++c) qf[c] = *(const short8*)(qp + c * 32 + lg * 8);
  }
  f32x4 o[8];
#pragma unroll
  for (int c = 0; c < 8; ++c) o[c] = (f32x4){0.f, 0.f, 0.f, 0.f};
  float lsum = 0.f;

  // K staging: 32 rows x 8 col-loaders (2x16B per thread)
  const int ksr = tid >> 3, ksc = (tid & 7) * 16;
  // V staging from VtG: rows vdr and 64+vdr, 4 threads per row (16B each)
  const int vdr = tid >> 2, vq = (tid & 3) * 8;
  const unsigned short* Vg = VtG + (size_t)(kvh * HD) * S_LEN;

  ushort8 kreg0, kreg1, vreg0, vreg1;
  auto loadKV = [&](int kt) {
    const unsigned short* kp = KVb + (size_t)(kt + ksr) * KVROW + kvh * HD + ksc;
    kreg0 = *(const ushort8*)kp;
    kreg1 = *(const ushort8*)(kp + 8);
    vreg0 = *(const ushort8*)(Vg + (size_t)vdr * S_LEN + kt + vq);
    vreg1 = *(const ushort8*)(Vg + (size_t)(64 + vdr) * S_LEN + kt + vq);
  };
  auto writeKV = [&](int b) {
    *(ushort8*)&Klds[b][ksr][ksc] = kreg0;
    *(ushort8*)&Klds[b][ksr][ksc + 8] = kreg1;
    *(ushort8*)&Vlds[b][vdr][vq] = vreg0;
    *(ushort8*)&Vlds[b][64 + vdr][vq] = vreg1;
  };

  loadKV(0);
  writeKV(0);

  const int nk = qb + 64;
  const int qr = qb + wid * 16 + lr;   // this lane's q-row
  const int qlim = qb + wid * 16 + 15; // wave-uniform causal bound
  const float SCALE = 0.08838834764831845f;
  int cur = 0;

  for (int kt = 0; kt < nk; kt += 32) {
    __syncthreads();  // buf[cur] ready
    const bool more = kt + 32 < nk;
    if (more) loadKV(kt + 32);  // in flight under compute

    if (kt <= qlim) {  // wave-uniform causal skip
      f32x4 sc[2];
      sc[0] = (f32x4){0.f, 0.f, 0.f, 0.f};
      sc[1] = (f32x4){0.f, 0.f, 0.f, 0.f};
      __builtin_amdgcn_s_setprio(1);
#pragma unroll
      for (int t = 0; t < 2; ++t)
#pragma unroll
        for (int c = 0; c < 4; ++c) {
          short8 kf = *(const short8*)&Klds[cur][t * 16 + lr][c * 32 + lg * 8];
          sc[t] = __builtin_amdgcn_mfma_f32_16x16x32_bf16(kf, qf[c], sc[t], 0, 0, 0);
        }
      __builtin_amdgcn_s_setprio(0);
      const unsigned mw = mbits[kt >> 5];
      float p[2][4];
#pragma unroll
      for (int t = 0; t < 2; ++t)
#pragma unroll
        for (int r = 0; r < 4; ++r) {
          int kk = t * 16 + lg * 4 + r;
          bool ok = (kt + kk <= qr) && ((mw >> kk) & 1u);
          float s = ok ? sc[t][r] * SCALE - 3.0f : -1e30f;
          float pv = __expf(s);
          p[t][r] = pv;
          lsum += pv;
        }
      // Pack p into 4 dwords (bf16 pairs) and exchange to A-frag layout:
      // lane (lr,lg) needs keys 8lg..8lg+7 = {W0,W1 | W2,W3} of lanes
      // lr+32*(lg&1) and +16 (t-half selected by lg<2).
      unsigned W0 = (unsigned)f2bf(p[0][0]) | ((unsigned)f2bf(p[0][1]) << 16);
      unsigned W1 = (unsigned)f2bf(p[0][2]) | ((unsigned)f2bf(p[0][3]) << 16);
      unsigned W2 = (unsigned)f2bf(p[1][0]) | ((unsigned)f2bf(p[1][1]) << 16);
      unsigned W3 = (unsigned)f2bf(p[1][2]) | ((unsigned)f2bf(p[1][3]) << 16);
      const int s0 = lr + ((lg & 1) << 5);
      const int s1 = s0 + 16;
      unsigned x0 = __shfl(W0, s0, 64), y0 = __shfl(W2, s0, 64);
      unsigned x1 = __shfl(W1, s0, 64), y1 = __shfl(W3, s0, 64);
      unsigned x2 = __shfl(W0, s1, 64), y2 = __shfl(W2, s1, 64);
      unsigned x3 = __shfl(W1, s1, 64), y3 = __shfl(W3, s1, 64);
      union { unsigned u[4]; short8 s8; } pu;
      const bool lo = (lg < 2);
      pu.u[0] = lo ? x0 : y0;
      pu.u[1] = lo ? x1 : y1;
      pu.u[2] = lo ? x2 : y2;
      pu.u[3] = lo ? x3 : y3;
      short8 pf = pu.s8;
      __builtin_amdgcn_s_setprio(1);
#pragma unroll
      for (int c = 0; c < 8; ++c) {
        short8 vf = *(const short8*)&Vlds[cur][c * 16 + lr][lg * 8];
        o[c] = __builtin_amdgcn_mfma_f32_16x16x32_bf16(pf, vf, o[c], 0, 0, 0);
      }
      __builtin_amdgcn_s_setprio(0);
    }
    if (more) writeKV(cur ^ 1);
    cur ^= 1;
  }

  // Row-sum totals: lanes {lr, lr+16, lr+32, lr+48} hold key-disjoint partials.
  float ls = lsum;
  ls += __shfl_xor(ls, 16, 64);
  ls += __shfl_xor(ls, 32, 64);
  float lrec[4];
#pragma unroll
  for (int r = 0; r < 4; ++r) lrec[r] = 1.0f / __shfl(ls, lg * 4 + r, 16);

#pragma unroll
  for (int c = 0; c < 8; ++c)
#pragma unroll
    for (int r = 0; r < 4; ++r) {
      const int row = qb + wid * 16 + lg * 4 + r;
      Ob[(size_t)row * HIDDIM + h * HD + c * 16 + lr] = f2bf(o[c][r] * lrec[r]);
    }
}

// ---------------------------------------------------------------------------
extern "C" void kernel_launch(void* const* d_in, const int* in_sizes, int n_in,
                              void* d_out, int out_size, void* d_ws, size_t ws_size,
                              hipStream_t stream) {
  const float* hidden = (const float*)d_in[0];
  const float* wq = (const float*)d_in[1];
  const float* wk = (const float*)d_in[2];
  const float* wv = (const float*)d_in[3];
  const float* wo = (const float*)d_in[4];
  const int* amask = (const int*)d_in[5];
  const int* pos = (const int*)d_in[6];

  unsigned short* Qb = (unsigned short*)d_ws;              // [2048][2048] bf16
  unsigned short* KVb = Qb + (size_t)S_LEN * HIDDIM;       // [2048][1024] K|V
  unsigned short* Ab = KVb + (size_t)S_LEN * KVROW;        // [2048][2048]
  unsigned short* WT1 = Ab + (size_t)S_LEN * HIDDIM;       // [3072][2048] Wqkv^T / Wo^T
  unsigned short* Hb = WT1 + (size_t)QKVN * HIDDIM;        // [2048][2048] bf16 hidden
  unsigned* mbits = (unsigned*)(Hb + (size_t)S_LEN * HIDDIM);
  unsigned short* Vt = WT1 + (size_t)HIDDIM * HIDDIM;      // alias Wk/WvT region,
                                                           // dead after QKV gemm
  float* out = (float*)d_out;

  dim3 blk(256);
  h2b_kernel<<<2048, blk, 0, stream>>>(hidden, Hb);
  transpose_w<<<dim3(32, 32), blk, 0, stream>>>(wq, WT1, HIDDIM, HIDDIM, 0);
  transpose_w<<<dim3(8, 32), blk, 0, stream>>>(wk, WT1, 512, HIDDIM, 2048);
  transpose_w<<<dim3(8, 32), blk, 0, stream>>>(wv, WT1, 512, HIDDIM, 2560);
  // Fused QKV projection: cols<2048 -> Qb, else -> KVb
  gemm_tn<false><<<dim3(QKVN / 64, S_LEN / 128), blk, 0, stream>>>(
      Hb, WT1, Qb, KVb, S_LEN, QKVN, HIDDIM, 2048, HIDDIM, KVROW);
  // V transpose into dead WkT/WvT region (V is not rope'd)
  transpose_v<<<dim3(8, 32), blk, 0, stream>>>(KVb, Vt);
  // Wo^T into WT1[0..2048) (Wq^T dead after QKV gemm)
  transpose_w<<<dim3(32, 32), blk, 0, stream>>>(wo, WT1, HIDDIM, HIDDIM, 0);
  rope2<<<(S_LEN * 64 + 255) / 256, blk, 0, stream>>>(Qb, KVb, pos);
  maskbits_kernel<<<1, 64, 0, stream>>>(amask, mbits);
  // Attention
  attn_kernel<<<dim3(S_LEN / 64, NH), blk, 0, stream>>>(Qb, KVb, Vt, mbits, Ab);
  // Output projection (fp32 out)
  gemm_tn<true><<<dim3(HIDDIM / 64, S_LEN / 128), blk, 0, stream>>>(
      Ab, WT1, out, nullptr, S_LEN, HIDDIM, HIDDIM, HIDDIM, HIDDIM, 0);
}

// Round 9
// 183.386 us; speedup vs baseline: 1.8469x; 1.1174x over previous
//
#include <hip/hip_runtime.h>
#include <hip/hip_bf16.h>

// Shapes (fixed for this problem)
#define S_LEN 2048
#define HIDDIM 2048
#define NH 16
#define NKV 4
#define HD 128
#define KVROW 1024   // KVb row = [K(512) | V(512)]
#define QKVN 3072    // fused projection width

typedef __attribute__((ext_vector_type(8))) short short8;
typedef __attribute__((ext_vector_type(8))) unsigned short ushort8;
typedef __attribute__((ext_vector_type(4))) unsigned short ushort4v;
typedef __attribute__((ext_vector_type(4))) float f32x4;

__device__ __forceinline__ unsigned short f2bf(float f) {
  union { float f; unsigned int u; } v; v.f = f;
  unsigned int r = (v.u + 0x7FFFu + ((v.u >> 16) & 1u)) >> 16;
  return (unsigned short)r;
}
__device__ __forceinline__ float bf2f(unsigned short h) {
  union { unsigned int u; float f; } v; v.u = ((unsigned int)h) << 16;
  return v.f;
}

// ---------------------------------------------------------------------------
// hidden fp32 -> bf16 (vectorized 8/thread)
// ---------------------------------------------------------------------------
__global__ __launch_bounds__(256) void h2b_kernel(const float* __restrict__ H,
                                                  unsigned short* __restrict__ Hb) {
  int i = (blockIdx.x * 256 + threadIdx.x) * 8;
  float4 a = *(const float4*)(H + i), b = *(const float4*)(H + i + 4);
  ushort8 r;
  r[0] = f2bf(a.x); r[1] = f2bf(a.y); r[2] = f2bf(a.z); r[3] = f2bf(a.w);
  r[4] = f2bf(b.x); r[5] = f2bf(b.y); r[6] = f2bf(b.z); r[7] = f2bf(b.w);
  *(ushort8*)(Hb + i) = r;
}

// ---------------------------------------------------------------------------
// Weight transpose: W[k][n] fp32 (row stride Nsrc) -> Wt[n_off+n][k] bf16
// (row stride Kdst). 64x64 tiles via LDS.
// ---------------------------------------------------------------------------
__global__ __launch_bounds__(256) void transpose_w(
    const float* __restrict__ W, unsigned short* __restrict__ Wt,
    int Nsrc, int Kdst, int n_off) {
  __shared__ unsigned short Ts[64][72];
  const int n0 = blockIdx.x * 64, k0 = blockIdx.y * 64;
  const int tid = threadIdx.x;
  const int c2 = (tid & 31) * 2, rb = tid >> 5;
#pragma unroll
  for (int p = 0; p < 8; ++p) {
    int r = rb + p * 8;
    float2 v = *(const float2*)&W[(size_t)(k0 + r) * Nsrc + n0 + c2];
    Ts[c2][r] = f2bf(v.x);
    Ts[c2 + 1][r] = f2bf(v.y);
  }
  __syncthreads();
  const int n = tid >> 2, kq = (tid & 3) * 16;
  ushort8 w0 = *(const ushort8*)&Ts[n][kq];
  ushort8 w1 = *(const ushort8*)&Ts[n][kq + 8];
  size_t base = (size_t)(n_off + n0 + n) * Kdst + k0 + kq;
  *(ushort8*)&Wt[base] = w0;
  *(ushort8*)&Wt[base + 8] = w1;
}

// ---------------------------------------------------------------------------
// V transpose: KVb[s][512+c] (bf16) -> Vt[c][s] (bf16), c<512, s<2048.
// ---------------------------------------------------------------------------
__global__ __launch_bounds__(256) void transpose_v(
    const unsigned short* __restrict__ KVb, unsigned short* __restrict__ Vt) {
  __shared__ unsigned short Ts[64][72];
  const int c0 = blockIdx.x * 64, s0 = blockIdx.y * 64;
  const int tid = threadIdx.x;
  const int sr = tid >> 2, cq = (tid & 3) * 16;
  ushort8 a = *(const ushort8*)&KVb[(size_t)(s0 + sr) * KVROW + 512 + c0 + cq];
  ushort8 b = *(const ushort8*)&KVb[(size_t)(s0 + sr) * KVROW + 512 + c0 + cq + 8];
#pragma unroll
  for (int j = 0; j < 8; ++j) { Ts[cq + j][sr] = a[j]; Ts[cq + 8 + j][sr] = b[j]; }
  __syncthreads();
  const int c = tid >> 2, sq = (tid & 3) * 16;
  ushort8 w0 = *(const ushort8*)&Ts[c][sq];
  ushort8 w1 = *(const ushort8*)&Ts[c][sq + 8];
  *(ushort8*)&Vt[(size_t)(c0 + c) * S_LEN + s0 + sq] = w0;
  *(ushort8*)&Vt[(size_t)(c0 + c) * S_LEN + s0 + sq + 8] = w1;
}

// ---------------------------------------------------------------------------
// MFMA GEMM (TN): C = A[M,K] @ Bt[N,K]^T, bf16 A. BM=128, BN=64, BK=64.
// ---------------------------------------------------------------------------
template <bool CF>
__global__ __launch_bounds__(256) void gemm_tn(
    const unsigned short* __restrict__ A, const unsigned short* __restrict__ Bt,
    void* __restrict__ C1, void* __restrict__ C2,
    int M, int N, int K, int splitcol, int ld1, int ld2) {
  __shared__ unsigned short As[128][72];
  __shared__ unsigned short Bs[64][72];
  const int m0 = blockIdx.y * 128, n0 = blockIdx.x * 64;
  const int tid = threadIdx.x, wid = tid >> 6, lane = tid & 63;
  const int wr = wid >> 1, wc = wid & 1;
  const int lr = lane & 15, lg = lane >> 4;

  f32x4 acc[4][2];
#pragma unroll
  for (int m = 0; m < 4; ++m)
#pragma unroll
    for (int n = 0; n < 2; ++n) acc[m][n] = (f32x4){0.f, 0.f, 0.f, 0.f};

  const int ar = tid >> 1, ac = (tid & 1) * 32;  // A: 128 rows x 2 half-rows
  const int br = tid >> 2, bc = (tid & 3) * 16;  // B: 64 rows x 4 chunks

  ushort8 areg[4], breg[2];
  auto loadA = [&](int k0) {
#pragma unroll
    for (int i = 0; i < 4; ++i)
      areg[i] = *(const ushort8*)(A + (size_t)(m0 + ar) * K + k0 + ac + i * 8);
  };
  auto loadB = [&](int k0) {
    breg[0] = *(const ushort8*)(Bt + (size_t)(n0 + br) * K + k0 + bc);
    breg[1] = *(const ushort8*)(Bt + (size_t)(n0 + br) * K + k0 + bc + 8);
  };
  auto writeS = [&]() {
#pragma unroll
    for (int i = 0; i < 4; ++i) *(ushort8*)&As[ar][ac + i * 8] = areg[i];
    *(ushort8*)&Bs[br][bc] = breg[0];
    *(ushort8*)&Bs[br][bc + 8] = breg[1];
  };

  loadA(0); loadB(0);
  writeS();

  for (int k0 = 0; k0 < K; k0 += 64) {
    __syncthreads();
    if (k0 + 64 < K) {
      loadA(k0 + 64); loadB(k0 + 64);
      asm volatile("" ::: "memory");  // pin prefetch issue before compute
    }
#pragma unroll
    for (int s = 0; s < 2; ++s) {
      short8 af[4], bfv[2];
#pragma unroll
      for (int m = 0; m < 4; ++m)
        af[m] = *(const short8*)&As[wr * 64 + m * 16 + lr][s * 32 + lg * 8];
#pragma unroll
      for (int n = 0; n < 2; ++n)
        bfv[n] = *(const short8*)&Bs[wc * 32 + n * 16 + lr][s * 32 + lg * 8];
#pragma unroll
      for (int m = 0; m < 4; ++m)
#pragma unroll
        for (int n = 0; n < 2; ++n)
          acc[m][n] = __builtin_amdgcn_mfma_f32_16x16x32_bf16(af[m], bfv[n], acc[m][n], 0, 0, 0);
    }
    __syncthreads();
    if (k0 + 64 < K) writeS();
  }

#pragma unroll
  for (int m = 0; m < 4; ++m)
#pragma unroll
    for (int n = 0; n < 2; ++n)
#pragma unroll
      for (int r = 0; r < 4; ++r) {
        int row = m0 + wr * 64 + m * 16 + lg * 4 + r;
        int col = n0 + wc * 32 + n * 16 + lr;
        float v = acc[m][n][r];
        if (CF) ((float*)C1)[(size_t)row * ld1 + col] = v;
        else if (col < splitcol) ((unsigned short*)C1)[(size_t)row * ld1 + col] = f2bf(v);
        else ((unsigned short*)C2)[(size_t)row * ld2 + (col - splitcol)] = f2bf(v);
      }
}

// ---------------------------------------------------------------------------
// RoPE: one thread per (s, j), trig once, applied to 16 Q + 4 K heads.
// ---------------------------------------------------------------------------
__global__ void rope2(unsigned short* __restrict__ Q,
                      unsigned short* __restrict__ KV,
                      const int* __restrict__ pos) {
  int idx = blockIdx.x * blockDim.x + threadIdx.x;
  if (idx >= S_LEN * 64) return;
  int s = idx >> 6, j = idx & 63;
  float inv = exp2f(-0.2076205059304703f * (float)j);  // 10000^(-j/64)
  float ang = (float)pos[s] * inv;
  float sn, cs;
  __sincosf(ang, &sn, &cs);
  auto rot = [&](unsigned short* base) {
    unsigned* p = (unsigned*)base;
    unsigned v = *p;
    float x0 = bf2f((unsigned short)(v & 0xffff));
    float x1 = bf2f((unsigned short)(v >> 16));
    unsigned r = (unsigned)f2bf(x0 * cs - x1 * sn) |
                 ((unsigned)f2bf(x0 * sn + x1 * cs) << 16);
    *p = r;
  };
#pragma unroll
  for (int hh = 0; hh < NH; ++hh) rot(Q + (size_t)s * HIDDIM + hh * HD + 2 * j);
#pragma unroll
  for (int hh = 0; hh < NKV; ++hh) rot(KV + (size_t)s * KVROW + hh * HD + 2 * j);
}

// ---------------------------------------------------------------------------
// Compact attention_mask [S] int32 -> bitmask words (1 bit per key).
// ---------------------------------------------------------------------------
__global__ void maskbits_kernel(const int* __restrict__ amask,
                                unsigned* __restrict__ mb) {
  int w = threadIdx.x;  // 64 words
  unsigned m = 0;
#pragma unroll
  for (int b = 0; b < 32; ++b) m |= (amask[w * 32 + b] != 0 ? 1u : 0u) << b;
  mb[w] = m;
}

// ---------------------------------------------------------------------------
// Flash attention v8: GQA-shared blocks. Block = (32 q-rows x kv-group),
// 512 threads = 8 waves = 4 heads x 2 row-groups; grid 64x4 = 256 blocks
// (1/CU). K/V tiles staged ONCE per kv-group (shared by 4 heads): one 16B
// load/thread for K and V each. LDS double-buffered, 1 barrier/tile,
// prefetch pinned early via asm memory fence. Swapped QK^T, static-max
// softmax, P routed through per-wave Plds (same-wave write->read, no
// barrier). setprio around MFMA clusters.
// ---------------------------------------------------------------------------
__global__ __launch_bounds__(512) void attn_kernel(
    const unsigned short* __restrict__ Qb, const unsigned short* __restrict__ KVb,
    const unsigned short* __restrict__ VtG, const unsigned* __restrict__ mbits,
    unsigned short* __restrict__ Ob) {
  __shared__ unsigned short Klds[2][32][136];  // K[key][d]
  __shared__ unsigned short Vlds[2][128][40];  // V^T[d][key]
  __shared__ unsigned short Plds[8][16][40];   // per-wave P[q][key]
  const int kvh = blockIdx.y;
  const int qt = 63 - (int)blockIdx.x;  // LPT: longest first
  const int qb = qt * 32;
  const int tid = threadIdx.x, wid = tid >> 6, lane = tid & 63;
  const int lr = lane & 15, lg = lane >> 4;
  const int h = kvh * 4 + (wid & 3);    // this wave's head
  const int rg = wid >> 2;              // row-group 0/1
  const int qrow0 = qb + rg * 16;

  short8 qf[4];
  {
    const unsigned short* qp = Qb + (size_t)(qrow0 + lr) * HIDDIM + h * HD;
#pragma unroll
    for (int c = 0; c < 4; ++c) qf[c] = *(const short8*)(qp + c * 32 + lg * 8);
  }
  f32x4 o[8];
#pragma unroll
  for (int c = 0; c < 8; ++c) o[c] = (f32x4){0.f, 0.f, 0.f, 0.f};
  float lsum = 0.f;

  // K staging: 32 rows x 16 col-loaders (1x16B per thread)
  const int ksr = tid >> 4, ksc = (tid & 15) * 8;
  // V staging from global V^T: 128 d-rows x 4 key-loaders (1x16B per thread)
  const int vdr = tid >> 2, vq = (tid & 3) * 8;
  const unsigned short* Vg = VtG + (size_t)(kvh * HD) * S_LEN;

  ushort8 kreg, vreg;
  auto loadKV = [&](int kt) {
    kreg = *(const ushort8*)(KVb + (size_t)(kt + ksr) * KVROW + kvh * HD + ksc);
    vreg = *(const ushort8*)(Vg + (size_t)vdr * S_LEN + kt + vq);
  };
  auto writeKV = [&](int b) {
    *(ushort8*)&Klds[b][ksr][ksc] = kreg;
    *(ushort8*)&Vlds[b][vdr][vq] = vreg;
  };

  loadKV(0);
  writeKV(0);

  const int nk = qb + 32;
  const int qr = qrow0 + lr;  // this lane's q-row
  const float SCALE = 0.08838834764831845f;
  int cur = 0;

  for (int kt = 0; kt < nk; kt += 32) {
    __syncthreads();  // buf[cur] ready
    const bool more = kt + 32 < nk;
    if (more) {
      loadKV(kt + 32);
      asm volatile("" ::: "memory");  // pin load issue before compute
    }

    f32x4 sc[2];
    sc[0] = (f32x4){0.f, 0.f, 0.f, 0.f};
    sc[1] = (f32x4){0.f, 0.f, 0.f, 0.f};
    __builtin_amdgcn_s_setprio(1);
#pragma unroll
    for (int t = 0; t < 2; ++t)
#pragma unroll
      for (int c = 0; c < 4; ++c) {
        short8 kf = *(const short8*)&Klds[cur][t * 16 + lr][c * 32 + lg * 8];
        sc[t] = __builtin_amdgcn_mfma_f32_16x16x32_bf16(kf, qf[c], sc[t], 0, 0, 0);
      }
    __builtin_amdgcn_s_setprio(0);
    const unsigned mw = mbits[kt >> 5];
    float p[2][4];
#pragma unroll
    for (int t = 0; t < 2; ++t)
#pragma unroll
      for (int r = 0; r < 4; ++r) {
        int kk = t * 16 + lg * 4 + r;
        bool ok = (kt + kk <= qr) && ((mw >> kk) & 1u);
        float s = ok ? sc[t][r] * SCALE - 3.0f : -1e30f;
        float pv = __expf(s);
        p[t][r] = pv;
        lsum += pv;
      }
    // P -> A-frag layout via per-wave LDS (same-wave write->read)
#pragma unroll
    for (int t = 0; t < 2; ++t) {
      ushort4v pk;
#pragma unroll
      for (int r = 0; r < 4; ++r) pk[r] = f2bf(p[t][r]);
      *(ushort4v*)&Plds[wid][lr][t * 16 + lg * 4] = pk;
    }
    short8 pf = *(const short8*)&Plds[wid][lr][lg * 8];
    __builtin_amdgcn_s_setprio(1);
#pragma unroll
    for (int c = 0; c < 8; ++c) {
      short8 vf = *(const short8*)&Vlds[cur][c * 16 + lr][lg * 8];
      o[c] = __builtin_amdgcn_mfma_f32_16x16x32_bf16(pf, vf, o[c], 0, 0, 0);
    }
    __builtin_amdgcn_s_setprio(0);

    if (more) writeKV(cur ^ 1);
    cur ^= 1;
  }

  // Row-sum totals: lanes {lr, lr+16, lr+32, lr+48} hold key-disjoint partials.
  float ls = lsum;
  ls += __shfl_xor(ls, 16, 64);
  ls += __shfl_xor(ls, 32, 64);
  float lrec[4];
#pragma unroll
  for (int r = 0; r < 4; ++r) lrec[r] = 1.0f / __shfl(ls, lg * 4 + r, 16);

#pragma unroll
  for (int c = 0; c < 8; ++c)
#pragma unroll
    for (int r = 0; r < 4; ++r) {
      const int row = qrow0 + lg * 4 + r;
      Ob[(size_t)row * HIDDIM + h * HD + c * 16 + lr] = f2bf(o[c][r] * lrec[r]);
    }
}

// ---------------------------------------------------------------------------
extern "C" void kernel_launch(void* const* d_in, const int* in_sizes, int n_in,
                              void* d_out, int out_size, void* d_ws, size_t ws_size,
                              hipStream_t stream) {
  const float* hidden = (const float*)d_in[0];
  const float* wq = (const float*)d_in[1];
  const float* wk = (const float*)d_in[2];
  const float* wv = (const float*)d_in[3];
  const float* wo = (const float*)d_in[4];
  const int* amask = (const int*)d_in[5];
  const int* pos = (const int*)d_in[6];

  unsigned short* Qb = (unsigned short*)d_ws;              // [2048][2048] bf16
  unsigned short* KVb = Qb + (size_t)S_LEN * HIDDIM;       // [2048][1024] K|V
  unsigned short* Ab = KVb + (size_t)S_LEN * KVROW;        // [2048][2048]
  unsigned short* WT1 = Ab + (size_t)S_LEN * HIDDIM;       // [3072][2048] Wqkv^T / Wo^T
  unsigned short* Hb = WT1 + (size_t)QKVN * HIDDIM;        // [2048][2048] bf16 hidden
  unsigned* mbits = (unsigned*)(Hb + (size_t)S_LEN * HIDDIM);
  unsigned short* Vt = WT1 + (size_t)HIDDIM * HIDDIM;      // alias Wk/WvT region,
                                                           // dead after QKV gemm
  float* out = (float*)d_out;

  dim3 blk(256);
  h2b_kernel<<<2048, blk, 0, stream>>>(hidden, Hb);
  transpose_w<<<dim3(32, 32), blk, 0, stream>>>(wq, WT1, HIDDIM, HIDDIM, 0);
  transpose_w<<<dim3(8, 32), blk, 0, stream>>>(wk, WT1, 512, HIDDIM, 2048);
  transpose_w<<<dim3(8, 32), blk, 0, stream>>>(wv, WT1, 512, HIDDIM, 2560);
  // Fused QKV projection: cols<2048 -> Qb, else -> KVb
  gemm_tn<false><<<dim3(QKVN / 64, S_LEN / 128), blk, 0, stream>>>(
      Hb, WT1, Qb, KVb, S_LEN, QKVN, HIDDIM, 2048, HIDDIM, KVROW);
  // V transpose into dead WkT/WvT region (V is not rope'd)
  transpose_v<<<dim3(8, 32), blk, 0, stream>>>(KVb, Vt);
  // Wo^T into WT1[0..2048) (Wq^T dead after QKV gemm)
  transpose_w<<<dim3(32, 32), blk, 0, stream>>>(wo, WT1, HIDDIM, HIDDIM, 0);
  rope2<<<(S_LEN * 64 + 255) / 256, blk, 0, stream>>>(Qb, KVb, pos);
  maskbits_kernel<<<1, 64, 0, stream>>>(amask, mbits);
  // Attention: block = (32 q-rows x kv-group), 8 waves
  attn_kernel<<<dim3(64, NKV), dim3(512), 0, stream>>>(Qb, KVb, Vt, mbits, Ab);
  // Output projection (fp32 out)
  gemm_tn<true><<<dim3(HIDDIM / 64, S_LEN / 128), blk, 0, stream>>>(
      Ab, WT1, out, nullptr, S_LEN, HIDDIM, HIDDIM, HIDDIM, HIDDIM, 0);
}